// Round 5
// baseline (140.084 us; speedup 1.0000x reference)
//
#include <hip/hip_runtime.h>
#include <hip/hip_bf16.h>
#include <math.h>

#define BB 32
#define NN 102400
#define TT 64
#define SS 1600
#define K3N (3 * NN)          // 307200
#define KC 64                 // K-chunk for GEMM1
#define NCHUNK (K3N / KC)     // 4800
#define XP 68                 // x tile row pad (floats)
#define WP 40                 // w1 tile row pad (floats)
#define PI_F 3.14159265358979323846f

// ---------------- K1: GEMM1 partials, double-buffered, all-b128 LDS reads.
// h_part[blk][b*32+c] = sum_{k in range} x[b,k]*w1[k,c]
// Thread map: ks = tid>>5 (8 consecutive k's each), tile = tid&31: bg=tile&7, cg=tile>>3.
// Output tile per thread: b = bg+8j (j=0..3), c = cg*8..cg*8+7.
__global__ __launch_bounds__(256, 4) void k1_gemm(const float* __restrict__ x,
                                                  const float* __restrict__ w1,
                                                  float* __restrict__ h_part,
                                                  int g1) {
    __shared__ float xs[2][32 * XP];     // 17408 B
    __shared__ float ws1[2][KC * WP];    // 20480 B
    const int tid = threadIdx.x;
    const int ks = tid >> 5;             // 0..7, owns k = ks*8 .. ks*8+7
    const int tile = tid & 31;
    const int bg = tile & 7;
    const int cg = tile >> 3;            // 0..3
    // staging roles (identical to R4 — measured conflict-free)
    const int sxb = tid >> 4, sxk = (tid & 15) * 4;   // x rows sxb, sxb+16
    const int swr = tid >> 3, swc = (tid & 7) * 4;    // w rows swr, swr+32

    float acc[4][8];
    #pragma unroll
    for (int j = 0; j < 4; ++j)
        #pragma unroll
        for (int c = 0; c < 8; ++c) acc[j][c] = 0.f;

    const int start = (int)(((long)blockIdx.x * NCHUNK) / g1);
    const int end   = (int)(((long)(blockIdx.x + 1) * NCHUNK) / g1);

    float4 rx0, rx1, rw0, rw1;
    {   // prologue
        const int k0 = start * KC;
        rx0 = *(const float4*)(x + (size_t)sxb * 6 * NN + k0 + sxk);
        rx1 = *(const float4*)(x + (size_t)(sxb + 16) * 6 * NN + k0 + sxk);
        rw0 = *(const float4*)(w1 + (size_t)(k0 + swr) * 32 + swc);
        rw1 = *(const float4*)(w1 + (size_t)(k0 + swr + 32) * 32 + swc);
        *(float4*)(xs[0] + sxb * XP + sxk) = rx0;
        *(float4*)(xs[0] + (sxb + 16) * XP + sxk) = rx1;
        *(float4*)(ws1[0] + swr * WP + swc) = rw0;
        *(float4*)(ws1[0] + (swr + 32) * WP + swc) = rw1;
    }
    __syncthreads();

    int cur = 0;
    for (int chunk = start; chunk < end; ++chunk) {
        const bool more = (chunk + 1) < end;
        if (more) {   // issue next chunk's loads early — fly under compute
            const int k0 = (chunk + 1) * KC;
            rx0 = *(const float4*)(x + (size_t)sxb * 6 * NN + k0 + sxk);
            rx1 = *(const float4*)(x + (size_t)(sxb + 16) * 6 * NN + k0 + sxk);
            rw0 = *(const float4*)(w1 + (size_t)(k0 + swr) * 32 + swc);
            rw1 = *(const float4*)(w1 + (size_t)(k0 + swr + 32) * 32 + swc);
        }
        const float* xc = xs[cur];
        const float* wc = ws1[cur];
        #pragma unroll
        for (int i = 0; i < 2; ++i) {
            const int kb0 = ks * 8 + i * 4;
            float4 xv[4];
            #pragma unroll
            for (int j = 0; j < 4; ++j)
                xv[j] = *(const float4*)(xc + (bg + 8 * j) * XP + kb0);
            #pragma unroll
            for (int kk = 0; kk < 4; ++kk) {
                const float4 wa = *(const float4*)(wc + (kb0 + kk) * WP + cg * 8);
                const float4 wb = *(const float4*)(wc + (kb0 + kk) * WP + cg * 8 + 4);
                #pragma unroll
                for (int j = 0; j < 4; ++j) {
                    const float xj = kk == 0 ? xv[j].x : (kk == 1 ? xv[j].y : (kk == 2 ? xv[j].z : xv[j].w));
                    acc[j][0] = fmaf(xj, wa.x, acc[j][0]);
                    acc[j][1] = fmaf(xj, wa.y, acc[j][1]);
                    acc[j][2] = fmaf(xj, wa.z, acc[j][2]);
                    acc[j][3] = fmaf(xj, wa.w, acc[j][3]);
                    acc[j][4] = fmaf(xj, wb.x, acc[j][4]);
                    acc[j][5] = fmaf(xj, wb.y, acc[j][5]);
                    acc[j][6] = fmaf(xj, wb.z, acc[j][6]);
                    acc[j][7] = fmaf(xj, wb.w, acc[j][7]);
                }
            }
        }
        if (more) {
            const int nb = cur ^ 1;
            *(float4*)(xs[nb] + sxb * XP + sxk) = rx0;
            *(float4*)(xs[nb] + (sxb + 16) * XP + sxk) = rx1;
            *(float4*)(ws1[nb] + swr * WP + swc) = rw0;
            *(float4*)(ws1[nb] + (swr + 32) * WP + swc) = rw1;
        }
        __syncthreads();
        cur ^= 1;
    }

    // reduce over ks: pair within wave (lane^32), then cross-wave via LDS
    #pragma unroll
    for (int j = 0; j < 4; ++j)
        #pragma unroll
        for (int c = 0; c < 8; ++c)
            acc[j][c] += __shfl_xor(acc[j][c], 32, 64);

    float* red = &xs[0][0];              // reuse x staging as scratch (4352 floats)
    const int wv = tid >> 6, lane = tid & 63;
    if (wv > 0 && lane < 32) {
        float* dst = red + (wv - 1) * 1152 + tile * 36;
        #pragma unroll
        for (int j = 0; j < 4; ++j) {
            float4 v0; v0.x = acc[j][0]; v0.y = acc[j][1]; v0.z = acc[j][2]; v0.w = acc[j][3];
            float4 v1; v1.x = acc[j][4]; v1.y = acc[j][5]; v1.z = acc[j][6]; v1.w = acc[j][7];
            *(float4*)(dst + j * 8) = v0;
            *(float4*)(dst + j * 8 + 4) = v1;
        }
    }
    __syncthreads();
    if (wv == 0 && lane < 32) {
        #pragma unroll
        for (int w2 = 0; w2 < 3; ++w2) {
            const float* srcp = red + w2 * 1152 + tile * 36;
            #pragma unroll
            for (int j = 0; j < 4; ++j) {
                const float4 v0 = *(const float4*)(srcp + j * 8);
                const float4 v1 = *(const float4*)(srcp + j * 8 + 4);
                acc[j][0] += v0.x; acc[j][1] += v0.y; acc[j][2] += v0.z; acc[j][3] += v0.w;
                acc[j][4] += v1.x; acc[j][5] += v1.y; acc[j][6] += v1.z; acc[j][7] += v1.w;
            }
        }
        float* hp = h_part + (size_t)blockIdx.x * 1024;
        #pragma unroll
        for (int j = 0; j < 4; ++j) {
            float4 v0; v0.x = acc[j][0]; v0.y = acc[j][1]; v0.z = acc[j][2]; v0.w = acc[j][3];
            float4 v1; v1.x = acc[j][4]; v1.y = acc[j][5]; v1.z = acc[j][6]; v1.w = acc[j][7];
            float* dst = hp + (bg + 8 * j) * 32 + cg * 8;
            *(float4*)(dst) = v0;
            *(float4*)(dst + 4) = v1;
        }
    }
}

// ---------------- KB: fused h-reduce + rigid params (blocks 0..31) and pts1 (blocks 32..95)
__global__ __launch_bounds__(256) void kb_fused(const float* __restrict__ h_part,
                                                const float* __restrict__ b1,
                                                const float* __restrict__ w2,
                                                const float* __restrict__ b2,
                                                const float* __restrict__ sz,
                                                const float* __restrict__ A,
                                                const int* __restrict__ tess,
                                                float* __restrict__ RT,
                                                float* __restrict__ pts1,
                                                int g1) {
    const int blk = blockIdx.x;
    if (blk < BB) {
        const int bb = blk;
        __shared__ float part[8][32];
        __shared__ float hsh[32];
        const int c = threadIdx.x & 31, g = threadIdx.x >> 5;
        float s = 0.f;
        for (int j = g; j < g1; j += 8) s += h_part[(size_t)j * 1024 + bb * 32 + c];
        part[g][c] = s;
        __syncthreads();
        if (threadIdx.x < 32) {
            float acc = 0.f;
            #pragma unroll
            for (int g2 = 0; g2 < 8; ++g2) acc += part[g2][threadIdx.x];
            hsh[threadIdx.x] = fmaxf(acc + b1[threadIdx.x], 0.f);
        }
        __syncthreads();
        const int t = threadIdx.x;
        if (t < TT) {
            float z[3];
            #pragma unroll
            for (int j = 0; j < 3; ++j) {
                const int col = 6 * t + 3 + j;
                float s2 = b2[col];
                #pragma unroll 8
                for (int cc = 0; cc < 32; ++cc) s2 = fmaf(hsh[cc], w2[cc * 384 + col], s2);
                z[j] = tanhf(s2);
            }
            float c0, s0, c1, s1, c2, s2v;
            sincosf(PI_F * z[0], &s0, &c0);
            sincosf(PI_F * z[1], &s1, &c1);
            sincosf(PI_F * z[2], &s2v, &c2);
            const float R00 = c0 * c1;
            const float R01 = -s0 * c2 + c0 * s1 * s2v;
            const float R02 = s0 * s2v + c0 * s1 * c2;
            const float R10 = s0 * c1;
            const float R11 = c0 * c2 + s0 * s1 * s2v;
            const float R12 = -c0 * s2v + s0 * s1 * c2;
            const float R20 = -s1;
            const float R21 = c1 * s2v;
            const float R22 = c1 * c2;
            const float szx = sz[0], szy = sz[1], szz = sz[2];
            const float cx = 0.5f * szx, cy = 0.5f * szy, cz = 0.5f * szz;
            const float T0 = z[0] * szx + cx - (cx * R00 + cy * R10 + cz * R20);
            const float T1 = z[1] * szy + cy - (cx * R01 + cy * R11 + cz * R21);
            const float T2 = z[2] * szz + cz - (cx * R02 + cy * R12 + cz * R22);
            float* o = RT + (bb * TT + t) * 12;
            o[0] = R00; o[1] = R10; o[2]  = R20; o[3]  = T0;
            o[4] = R01; o[5] = R11; o[6]  = R21; o[7]  = T1;
            o[8] = R02; o[9] = R12; o[10] = R22; o[11] = T2;
        }
    } else {
        const int t = blk - BB;
        const int* tr = tess + t * SS;
        float s0 = 0.f, s1 = 0.f, s2 = 0.f;
        for (int s = threadIdx.x; s < SS; s += 256) {
            const int idx = tr[s];
            s0 += A[idx]; s1 += A[NN + idx]; s2 += A[2 * NN + idx];
        }
        #pragma unroll
        for (int o = 32; o > 0; o >>= 1) {
            s0 += __shfl_down(s0, o, 64);
            s1 += __shfl_down(s1, o, 64);
            s2 += __shfl_down(s2, o, 64);
        }
        __shared__ float red[4 * 3];
        const int lane = threadIdx.x & 63, wv = threadIdx.x >> 6;
        if (lane == 0) { red[wv * 3] = s0; red[wv * 3 + 1] = s1; red[wv * 3 + 2] = s2; }
        __syncthreads();
        if (threadIdx.x < 3) {
            const float s = red[threadIdx.x] + red[3 + threadIdx.x] + red[6 + threadIdx.x] + red[9 + threadIdx.x];
            pts1[t * 3 + threadIdx.x] = s * (1.0f / SS);
        }
    }
}

// ---------------- K3: transform + scatter + hi-copy + pts2 accumulation
__global__ __launch_bounds__(256) void k3_transform(const float* __restrict__ x,
                                                    const int* __restrict__ tess,
                                                    const float* __restrict__ RT,
                                                    float* __restrict__ out,
                                                    float* __restrict__ pts2) {
    const int blk = blockIdx.x;
    const int b = blk / TT, t = blk % TT;
    const float* p = RT + blk * 12;
    const float M00 = p[0], M01 = p[1], M02 = p[2], T0 = p[3];
    const float M10 = p[4], M11 = p[5], M12 = p[6], T1 = p[7];
    const float M20 = p[8], M21 = p[9], M22 = p[10], T2 = p[11];
    const float* xb = x + (size_t)b * 6 * NN;
    float* ob = out + (size_t)b * 6 * NN;
    const int* tr = tess + t * SS;
    float s0 = 0.f, s1 = 0.f, s2 = 0.f;
    for (int s = threadIdx.x; s < SS; s += 256) {
        const int idx = tr[s];
        const float x0 = xb[idx], x1 = xb[NN + idx], x2 = xb[2 * NN + idx];
        const float y0 = fmaf(M00, x0, fmaf(M01, x1, fmaf(M02, x2, T0)));
        const float y1 = fmaf(M10, x0, fmaf(M11, x1, fmaf(M12, x2, T1)));
        const float y2 = fmaf(M20, x0, fmaf(M21, x1, fmaf(M22, x2, T2)));
        ob[idx] = y0; ob[NN + idx] = y1; ob[2 * NN + idx] = y2;
        s0 += y0; s1 += y1; s2 += y2;
    }
    const int n0 = t * SS;
    for (int i = threadIdx.x; i < 1200; i += 256) {
        const int ch = i / 400, r = i - ch * 400;
        const size_t off = (size_t)(3 + ch) * NN + n0 + r * 4;
        *(float4*)(ob + off) = *(const float4*)(xb + off);
    }
    #pragma unroll
    for (int o = 32; o > 0; o >>= 1) {
        s0 += __shfl_down(s0, o, 64);
        s1 += __shfl_down(s1, o, 64);
        s2 += __shfl_down(s2, o, 64);
    }
    __shared__ float red[4 * 3];
    const int lane = threadIdx.x & 63, wv = threadIdx.x >> 6;
    if (lane == 0) { red[wv * 3] = s0; red[wv * 3 + 1] = s1; red[wv * 3 + 2] = s2; }
    __syncthreads();
    if (threadIdx.x < 3) {
        const float s = red[threadIdx.x] + red[3 + threadIdx.x] + red[6 + threadIdx.x] + red[9 + threadIdx.x];
        pts2[blk * 3 + threadIdx.x] = s * (1.0f / SS);
    }
}

// ---------------- K5: reg[b] = sum_{t,u} (mask[t,u]*(d1[t,u]-d2[b,t,u]))^2
__global__ __launch_bounds__(256) void k5_reg(const float* __restrict__ pts1,
                                              const float* __restrict__ pts2,
                                              const float* __restrict__ mask,
                                              float* __restrict__ out) {
    const int b = blockIdx.x;
    __shared__ float p1[TT * 3], p2[TT * 3];
    for (int i = threadIdx.x; i < TT * 3; i += 256) {
        p1[i] = pts1[i];
        p2[i] = pts2[b * TT * 3 + i];
    }
    __syncthreads();
    float acc = 0.f;
    for (int pr = threadIdx.x; pr < TT * TT; pr += 256) {
        const int t = pr >> 6, u = pr & 63;
        float dx = p1[t * 3] - p1[u * 3];
        float dy = p1[t * 3 + 1] - p1[u * 3 + 1];
        float dz = p1[t * 3 + 2] - p1[u * 3 + 2];
        const float d1 = sqrtf(dx * dx + dy * dy + dz * dz + 1e-12f);
        dx = p2[t * 3] - p2[u * 3];
        dy = p2[t * 3 + 1] - p2[u * 3 + 1];
        dz = p2[t * 3 + 2] - p2[u * 3 + 2];
        const float d2 = sqrtf(dx * dx + dy * dy + dz * dz + 1e-12f);
        const float d = mask[pr] * (d1 - d2);
        acc = fmaf(d, d, acc);
    }
    #pragma unroll
    for (int o = 32; o > 0; o >>= 1) acc += __shfl_down(acc, o, 64);
    __shared__ float red[4];
    const int lane = threadIdx.x & 63, wv = threadIdx.x >> 6;
    if (lane == 0) red[wv] = acc;
    __syncthreads();
    if (threadIdx.x == 0) {
        out[(size_t)BB * 6 * NN + b] = red[0] + red[1] + red[2] + red[3];
    }
}

extern "C" void kernel_launch(void* const* d_in, const int* in_sizes, int n_in,
                              void* d_out, int out_size, void* d_ws, size_t ws_size,
                              hipStream_t stream) {
    const float* x    = (const float*)d_in[0];
    const float* w1   = (const float*)d_in[1];
    const float* b1   = (const float*)d_in[2];
    const float* w2   = (const float*)d_in[3];
    const float* b2   = (const float*)d_in[4];
    const float* A    = (const float*)d_in[5];
    const float* mask = (const float*)d_in[6];
    const float* sz   = (const float*)d_in[7];
    const int*   tess = (const int*)d_in[8];
    float* out = (float*)d_out;
    float* ws  = (float*)d_ws;

    // adaptive GEMM1 grid: prefer 1024 blocks (4/CU) if workspace allows
    int g1 = 1024;
    while ((size_t)((size_t)g1 * 1024 + 2048 * 12 + 2048 * 3 + 192) * 4 > ws_size && g1 > 128) g1 >>= 1;

    float* h_part = ws;                           // g1*1024
    float* RT     = h_part + (size_t)g1 * 1024;   // 2048*12
    float* pts2   = RT + BB * TT * 12;            // 2048*3
    float* pts1   = pts2 + BB * TT * 3;           // 64*3

    k1_gemm<<<g1, 256, 0, stream>>>(x, w1, h_part, g1);
    kb_fused<<<BB + TT, 256, 0, stream>>>(h_part, b1, w2, b2, sz, A, tess, RT, pts1, g1);
    k3_transform<<<BB * TT, 256, 0, stream>>>(x, tess, RT, out, pts2);
    k5_reg<<<BB, 256, 0, stream>>>(pts1, pts2, mask, out);
}

// Round 6
// 95.210 us; speedup vs baseline: 1.4713x; 1.4713x over previous
//
#include <hip/hip_runtime.h>
#include <hip/hip_bf16.h>
#include <math.h>

#define BB 32
#define NN 102400
#define TT 64
#define SS 1600
#define K3N (3 * NN)          // 307200
#define KC 64                 // K-chunk for GEMM1
#define NCHUNK (K3N / KC)     // 4800
#define XP 68                 // x tile row pad (floats)
#define WP 40                 // w1 tile row pad (floats)
#define PI_F 3.14159265358979323846f

// ---------------- K1: GEMM1 partials, double-buffered, all-b128 LDS reads.
// h_part[blk][b*32+c] = sum_{k in range} x[b,k]*w1[k,c]
// Thread map: ks = tid>>5 (8 consecutive k's each), tile = tid&31: bg=tile&7, cg=tile>>3.
// NOTE: no min-waves clamp — R5's __launch_bounds__(256,4) forced VGPR=64 and
// spilled ~30 regs to scratch (WRITE_SIZE 126 MB, FETCH +30 MB). LDS (37.9 KB)
// caps occupancy at 4 blocks/CU anyway.
__global__ __launch_bounds__(256) void k1_gemm(const float* __restrict__ x,
                                               const float* __restrict__ w1,
                                               float* __restrict__ h_part,
                                               int g1) {
    __shared__ float xs[2][32 * XP];     // 17408 B
    __shared__ float ws1[2][KC * WP];    // 20480 B
    const int tid = threadIdx.x;
    const int ks = tid >> 5;             // 0..7, owns k = ks*8 .. ks*8+7
    const int tile = tid & 31;
    const int bg = tile & 7;
    const int cg = tile >> 3;            // 0..3
    // staging roles (identical to R4 — measured conflict-free)
    const int sxb = tid >> 4, sxk = (tid & 15) * 4;   // x rows sxb, sxb+16
    const int swr = tid >> 3, swc = (tid & 7) * 4;    // w rows swr, swr+32

    float acc[4][8];
    #pragma unroll
    for (int j = 0; j < 4; ++j)
        #pragma unroll
        for (int c = 0; c < 8; ++c) acc[j][c] = 0.f;

    const int start = (int)(((long)blockIdx.x * NCHUNK) / g1);
    const int end   = (int)(((long)(blockIdx.x + 1) * NCHUNK) / g1);

    float4 rx0, rx1, rw0, rw1;
    {   // prologue
        const int k0 = start * KC;
        rx0 = *(const float4*)(x + (size_t)sxb * 6 * NN + k0 + sxk);
        rx1 = *(const float4*)(x + (size_t)(sxb + 16) * 6 * NN + k0 + sxk);
        rw0 = *(const float4*)(w1 + (size_t)(k0 + swr) * 32 + swc);
        rw1 = *(const float4*)(w1 + (size_t)(k0 + swr + 32) * 32 + swc);
        *(float4*)(xs[0] + sxb * XP + sxk) = rx0;
        *(float4*)(xs[0] + (sxb + 16) * XP + sxk) = rx1;
        *(float4*)(ws1[0] + swr * WP + swc) = rw0;
        *(float4*)(ws1[0] + (swr + 32) * WP + swc) = rw1;
    }
    __syncthreads();

    int cur = 0;
    for (int chunk = start; chunk < end; ++chunk) {
        const bool more = (chunk + 1) < end;
        if (more) {   // issue next chunk's loads early — fly under compute
            const int k0 = (chunk + 1) * KC;
            rx0 = *(const float4*)(x + (size_t)sxb * 6 * NN + k0 + sxk);
            rx1 = *(const float4*)(x + (size_t)(sxb + 16) * 6 * NN + k0 + sxk);
            rw0 = *(const float4*)(w1 + (size_t)(k0 + swr) * 32 + swc);
            rw1 = *(const float4*)(w1 + (size_t)(k0 + swr + 32) * 32 + swc);
        }
        const float* xc = xs[cur];
        const float* wc = ws1[cur];
        #pragma unroll
        for (int i = 0; i < 2; ++i) {
            const int kb0 = ks * 8 + i * 4;
            float4 xv[4];
            #pragma unroll
            for (int j = 0; j < 4; ++j)
                xv[j] = *(const float4*)(xc + (bg + 8 * j) * XP + kb0);
            #pragma unroll
            for (int kk = 0; kk < 4; ++kk) {
                const float4 wa = *(const float4*)(wc + (kb0 + kk) * WP + cg * 8);
                const float4 wb = *(const float4*)(wc + (kb0 + kk) * WP + cg * 8 + 4);
                #pragma unroll
                for (int j = 0; j < 4; ++j) {
                    const float xj = kk == 0 ? xv[j].x : (kk == 1 ? xv[j].y : (kk == 2 ? xv[j].z : xv[j].w));
                    acc[j][0] = fmaf(xj, wa.x, acc[j][0]);
                    acc[j][1] = fmaf(xj, wa.y, acc[j][1]);
                    acc[j][2] = fmaf(xj, wa.z, acc[j][2]);
                    acc[j][3] = fmaf(xj, wa.w, acc[j][3]);
                    acc[j][4] = fmaf(xj, wb.x, acc[j][4]);
                    acc[j][5] = fmaf(xj, wb.y, acc[j][5]);
                    acc[j][6] = fmaf(xj, wb.z, acc[j][6]);
                    acc[j][7] = fmaf(xj, wb.w, acc[j][7]);
                }
            }
        }
        if (more) {
            const int nb = cur ^ 1;
            *(float4*)(xs[nb] + sxb * XP + sxk) = rx0;
            *(float4*)(xs[nb] + (sxb + 16) * XP + sxk) = rx1;
            *(float4*)(ws1[nb] + swr * WP + swc) = rw0;
            *(float4*)(ws1[nb] + (swr + 32) * WP + swc) = rw1;
        }
        __syncthreads();
        cur ^= 1;
    }

    // reduce over ks: pair within wave (lane^32), then cross-wave via LDS
    #pragma unroll
    for (int j = 0; j < 4; ++j)
        #pragma unroll
        for (int c = 0; c < 8; ++c)
            acc[j][c] += __shfl_xor(acc[j][c], 32, 64);

    float* red = &xs[0][0];              // reuse x staging as scratch (4352 floats)
    const int wv = tid >> 6, lane = tid & 63;
    if (wv > 0 && lane < 32) {
        float* dst = red + (wv - 1) * 1152 + tile * 36;
        #pragma unroll
        for (int j = 0; j < 4; ++j) {
            float4 v0; v0.x = acc[j][0]; v0.y = acc[j][1]; v0.z = acc[j][2]; v0.w = acc[j][3];
            float4 v1; v1.x = acc[j][4]; v1.y = acc[j][5]; v1.z = acc[j][6]; v1.w = acc[j][7];
            *(float4*)(dst + j * 8) = v0;
            *(float4*)(dst + j * 8 + 4) = v1;
        }
    }
    __syncthreads();
    if (wv == 0 && lane < 32) {
        #pragma unroll
        for (int w2 = 0; w2 < 3; ++w2) {
            const float* srcp = red + w2 * 1152 + tile * 36;
            #pragma unroll
            for (int j = 0; j < 4; ++j) {
                const float4 v0 = *(const float4*)(srcp + j * 8);
                const float4 v1 = *(const float4*)(srcp + j * 8 + 4);
                acc[j][0] += v0.x; acc[j][1] += v0.y; acc[j][2] += v0.z; acc[j][3] += v0.w;
                acc[j][4] += v1.x; acc[j][5] += v1.y; acc[j][6] += v1.z; acc[j][7] += v1.w;
            }
        }
        float* hp = h_part + (size_t)blockIdx.x * 1024;
        #pragma unroll
        for (int j = 0; j < 4; ++j) {
            float4 v0; v0.x = acc[j][0]; v0.y = acc[j][1]; v0.z = acc[j][2]; v0.w = acc[j][3];
            float4 v1; v1.x = acc[j][4]; v1.y = acc[j][5]; v1.z = acc[j][6]; v1.w = acc[j][7];
            float* dst = hp + (bg + 8 * j) * 32 + cg * 8;
            *(float4*)(dst) = v0;
            *(float4*)(dst + 4) = v1;
        }
    }
}

// ---------------- KB: fused h-reduce + rigid params (blocks 0..31) and pts1 (blocks 32..95)
__global__ __launch_bounds__(256) void kb_fused(const float* __restrict__ h_part,
                                                const float* __restrict__ b1,
                                                const float* __restrict__ w2,
                                                const float* __restrict__ b2,
                                                const float* __restrict__ sz,
                                                const float* __restrict__ A,
                                                const int* __restrict__ tess,
                                                float* __restrict__ RT,
                                                float* __restrict__ pts1,
                                                int g1) {
    const int blk = blockIdx.x;
    if (blk < BB) {
        const int bb = blk;
        __shared__ float part[8][32];
        __shared__ float hsh[32];
        const int c = threadIdx.x & 31, g = threadIdx.x >> 5;
        float s = 0.f;
        for (int j = g; j < g1; j += 8) s += h_part[(size_t)j * 1024 + bb * 32 + c];
        part[g][c] = s;
        __syncthreads();
        if (threadIdx.x < 32) {
            float acc = 0.f;
            #pragma unroll
            for (int g2 = 0; g2 < 8; ++g2) acc += part[g2][threadIdx.x];
            hsh[threadIdx.x] = fmaxf(acc + b1[threadIdx.x], 0.f);
        }
        __syncthreads();
        const int t = threadIdx.x;
        if (t < TT) {
            float z[3];
            #pragma unroll
            for (int j = 0; j < 3; ++j) {
                const int col = 6 * t + 3 + j;
                float s2 = b2[col];
                #pragma unroll 8
                for (int cc = 0; cc < 32; ++cc) s2 = fmaf(hsh[cc], w2[cc * 384 + col], s2);
                z[j] = tanhf(s2);
            }
            float c0, s0, c1, s1, c2, s2v;
            sincosf(PI_F * z[0], &s0, &c0);
            sincosf(PI_F * z[1], &s1, &c1);
            sincosf(PI_F * z[2], &s2v, &c2);
            const float R00 = c0 * c1;
            const float R01 = -s0 * c2 + c0 * s1 * s2v;
            const float R02 = s0 * s2v + c0 * s1 * c2;
            const float R10 = s0 * c1;
            const float R11 = c0 * c2 + s0 * s1 * s2v;
            const float R12 = -c0 * s2v + s0 * s1 * c2;
            const float R20 = -s1;
            const float R21 = c1 * s2v;
            const float R22 = c1 * c2;
            const float szx = sz[0], szy = sz[1], szz = sz[2];
            const float cx = 0.5f * szx, cy = 0.5f * szy, cz = 0.5f * szz;
            const float T0 = z[0] * szx + cx - (cx * R00 + cy * R10 + cz * R20);
            const float T1 = z[1] * szy + cy - (cx * R01 + cy * R11 + cz * R21);
            const float T2 = z[2] * szz + cz - (cx * R02 + cy * R12 + cz * R22);
            float* o = RT + (bb * TT + t) * 12;
            o[0] = R00; o[1] = R10; o[2]  = R20; o[3]  = T0;
            o[4] = R01; o[5] = R11; o[6]  = R21; o[7]  = T1;
            o[8] = R02; o[9] = R12; o[10] = R22; o[11] = T2;
        }
    } else {
        const int t = blk - BB;
        const int* tr = tess + t * SS;
        float s0 = 0.f, s1 = 0.f, s2 = 0.f;
        for (int s = threadIdx.x; s < SS; s += 256) {
            const int idx = tr[s];
            s0 += A[idx]; s1 += A[NN + idx]; s2 += A[2 * NN + idx];
        }
        #pragma unroll
        for (int o = 32; o > 0; o >>= 1) {
            s0 += __shfl_down(s0, o, 64);
            s1 += __shfl_down(s1, o, 64);
            s2 += __shfl_down(s2, o, 64);
        }
        __shared__ float red[4 * 3];
        const int lane = threadIdx.x & 63, wv = threadIdx.x >> 6;
        if (lane == 0) { red[wv * 3] = s0; red[wv * 3 + 1] = s1; red[wv * 3 + 2] = s2; }
        __syncthreads();
        if (threadIdx.x < 3) {
            const float s = red[threadIdx.x] + red[3 + threadIdx.x] + red[6 + threadIdx.x] + red[9 + threadIdx.x];
            pts1[t * 3 + threadIdx.x] = s * (1.0f / SS);
        }
    }
}

// ---------------- K3: transform + scatter + hi-copy + pts2 accumulation
__global__ __launch_bounds__(256) void k3_transform(const float* __restrict__ x,
                                                    const int* __restrict__ tess,
                                                    const float* __restrict__ RT,
                                                    float* __restrict__ out,
                                                    float* __restrict__ pts2) {
    const int blk = blockIdx.x;
    const int b = blk / TT, t = blk % TT;
    const float* p = RT + blk * 12;
    const float M00 = p[0], M01 = p[1], M02 = p[2], T0 = p[3];
    const float M10 = p[4], M11 = p[5], M12 = p[6], T1 = p[7];
    const float M20 = p[8], M21 = p[9], M22 = p[10], T2 = p[11];
    const float* xb = x + (size_t)b * 6 * NN;
    float* ob = out + (size_t)b * 6 * NN;
    const int* tr = tess + t * SS;
    float s0 = 0.f, s1 = 0.f, s2 = 0.f;
    for (int s = threadIdx.x; s < SS; s += 256) {
        const int idx = tr[s];
        const float x0 = xb[idx], x1 = xb[NN + idx], x2 = xb[2 * NN + idx];
        const float y0 = fmaf(M00, x0, fmaf(M01, x1, fmaf(M02, x2, T0)));
        const float y1 = fmaf(M10, x0, fmaf(M11, x1, fmaf(M12, x2, T1)));
        const float y2 = fmaf(M20, x0, fmaf(M21, x1, fmaf(M22, x2, T2)));
        ob[idx] = y0; ob[NN + idx] = y1; ob[2 * NN + idx] = y2;
        s0 += y0; s1 += y1; s2 += y2;
    }
    const int n0 = t * SS;
    for (int i = threadIdx.x; i < 1200; i += 256) {
        const int ch = i / 400, r = i - ch * 400;
        const size_t off = (size_t)(3 + ch) * NN + n0 + r * 4;
        *(float4*)(ob + off) = *(const float4*)(xb + off);
    }
    #pragma unroll
    for (int o = 32; o > 0; o >>= 1) {
        s0 += __shfl_down(s0, o, 64);
        s1 += __shfl_down(s1, o, 64);
        s2 += __shfl_down(s2, o, 64);
    }
    __shared__ float red[4 * 3];
    const int lane = threadIdx.x & 63, wv = threadIdx.x >> 6;
    if (lane == 0) { red[wv * 3] = s0; red[wv * 3 + 1] = s1; red[wv * 3 + 2] = s2; }
    __syncthreads();
    if (threadIdx.x < 3) {
        const float s = red[threadIdx.x] + red[3 + threadIdx.x] + red[6 + threadIdx.x] + red[9 + threadIdx.x];
        pts2[blk * 3 + threadIdx.x] = s * (1.0f / SS);
    }
}

// ---------------- K5: reg[b] = sum_{t,u} (mask[t,u]*(d1[t,u]-d2[b,t,u]))^2
__global__ __launch_bounds__(256) void k5_reg(const float* __restrict__ pts1,
                                              const float* __restrict__ pts2,
                                              const float* __restrict__ mask,
                                              float* __restrict__ out) {
    const int b = blockIdx.x;
    __shared__ float p1[TT * 3], p2[TT * 3];
    for (int i = threadIdx.x; i < TT * 3; i += 256) {
        p1[i] = pts1[i];
        p2[i] = pts2[b * TT * 3 + i];
    }
    __syncthreads();
    float acc = 0.f;
    for (int pr = threadIdx.x; pr < TT * TT; pr += 256) {
        const int t = pr >> 6, u = pr & 63;
        float dx = p1[t * 3] - p1[u * 3];
        float dy = p1[t * 3 + 1] - p1[u * 3 + 1];
        float dz = p1[t * 3 + 2] - p1[u * 3 + 2];
        const float d1 = sqrtf(dx * dx + dy * dy + dz * dz + 1e-12f);
        dx = p2[t * 3] - p2[u * 3];
        dy = p2[t * 3 + 1] - p2[u * 3 + 1];
        dz = p2[t * 3 + 2] - p2[u * 3 + 2];
        const float d2 = sqrtf(dx * dx + dy * dy + dz * dz + 1e-12f);
        const float d = mask[pr] * (d1 - d2);
        acc = fmaf(d, d, acc);
    }
    #pragma unroll
    for (int o = 32; o > 0; o >>= 1) acc += __shfl_down(acc, o, 64);
    __shared__ float red[4];
    const int lane = threadIdx.x & 63, wv = threadIdx.x >> 6;
    if (lane == 0) red[wv] = acc;
    __syncthreads();
    if (threadIdx.x == 0) {
        out[(size_t)BB * 6 * NN + b] = red[0] + red[1] + red[2] + red[3];
    }
}

extern "C" void kernel_launch(void* const* d_in, const int* in_sizes, int n_in,
                              void* d_out, int out_size, void* d_ws, size_t ws_size,
                              hipStream_t stream) {
    const float* x    = (const float*)d_in[0];
    const float* w1   = (const float*)d_in[1];
    const float* b1   = (const float*)d_in[2];
    const float* w2   = (const float*)d_in[3];
    const float* b2   = (const float*)d_in[4];
    const float* A    = (const float*)d_in[5];
    const float* mask = (const float*)d_in[6];
    const float* sz   = (const float*)d_in[7];
    const int*   tess = (const int*)d_in[8];
    float* out = (float*)d_out;
    float* ws  = (float*)d_ws;

    // adaptive GEMM1 grid: prefer 1024 blocks (4/CU) if workspace allows
    int g1 = 1024;
    while ((size_t)((size_t)g1 * 1024 + 2048 * 12 + 2048 * 3 + 192) * 4 > ws_size && g1 > 128) g1 >>= 1;

    float* h_part = ws;                           // g1*1024
    float* RT     = h_part + (size_t)g1 * 1024;   // 2048*12
    float* pts2   = RT + BB * TT * 12;            // 2048*3
    float* pts1   = pts2 + BB * TT * 3;           // 64*3

    k1_gemm<<<g1, 256, 0, stream>>>(x, w1, h_part, g1);
    kb_fused<<<BB + TT, 256, 0, stream>>>(h_part, b1, w2, b2, sz, A, tess, RT, pts1, g1);
    k3_transform<<<BB * TT, 256, 0, stream>>>(x, tess, RT, out, pts2);
    k5_reg<<<BB, 256, 0, stream>>>(pts1, pts2, mask, out);
}

// Round 7
// 74.642 us; speedup vs baseline: 1.8767x; 1.2756x over previous
//
#include <hip/hip_runtime.h>
#include <hip/hip_bf16.h>
#include <math.h>

#define BB 32
#define NN 102400
#define TT 64
#define SS 1600
#define K3N (3 * NN)          // 307200
#define KC 64                 // K-chunk for GEMM1
#define G1 512                // gemm blocks (proven R4 config)
#define CPB 512               // hi-channel copy blocks
#define NCHUNK (K3N / KC)     // 4800
#define XP 68                 // x tile row pad (floats)
#define WP 40                 // w1 tile row pad (floats)
#define PI_F 3.14159265358979323846f

// ---------------- K1 mega-kernel:
//   blocks [0, G1)           : GEMM1 partials (verbatim R4-winning double-buffered loop)
//   blocks [G1, G1+CPB)      : copy channels 3..5 x->out (float4 stream, independent work)
//   blocks [G1+CPB, +TT)     : pts1[t] = mean_s A[:3][tess[t,s]]
__global__ __launch_bounds__(256) void k1_mega(const float* __restrict__ x,
                                               const float* __restrict__ w1,
                                               const float* __restrict__ A,
                                               const int* __restrict__ tess,
                                               float* __restrict__ h_part,
                                               float* __restrict__ out,
                                               float* __restrict__ pts1) {
    const int tid = threadIdx.x;
    if (blockIdx.x < G1) {
        // ---- GEMM partials: h_part[blk][b*32+c] = sum_k x[b,k]*w1[k,c]
        // Thread tile: 4 b's (stride 8) x 8 c's, k-split 8 across consecutive lanes.
        __shared__ float xs[2][32 * XP];
        __shared__ float ws1[2][KC * WP];
        const int ks = tid & 7;
        const int tile = tid >> 3;
        const int bg = tile & 7;
        const int cg = tile >> 3;
        const int sxb = tid >> 4, sxk = (tid & 15) * 4;
        const int swr = tid >> 3, swc = (tid & 7) * 4;

        float acc[4][8];
        #pragma unroll
        for (int j = 0; j < 4; ++j)
            #pragma unroll
            for (int c = 0; c < 8; ++c) acc[j][c] = 0.f;

        const int start = (int)(((long)blockIdx.x * NCHUNK) / G1);
        const int end   = (int)(((long)(blockIdx.x + 1) * NCHUNK) / G1);

        float4 rx0, rx1, rw0, rw1;
        {
            const int k0 = start * KC;
            rx0 = *(const float4*)(x + (size_t)sxb * 6 * NN + k0 + sxk);
            rx1 = *(const float4*)(x + (size_t)(sxb + 16) * 6 * NN + k0 + sxk);
            rw0 = *(const float4*)(w1 + (size_t)(k0 + swr) * 32 + swc);
            rw1 = *(const float4*)(w1 + (size_t)(k0 + swr + 32) * 32 + swc);
            *(float4*)(xs[0] + sxb * XP + sxk) = rx0;
            *(float4*)(xs[0] + (sxb + 16) * XP + sxk) = rx1;
            *(float4*)(ws1[0] + swr * WP + swc) = rw0;
            *(float4*)(ws1[0] + (swr + 32) * WP + swc) = rw1;
        }
        __syncthreads();

        int cur = 0;
        for (int chunk = start; chunk < end; ++chunk) {
            const bool more = (chunk + 1) < end;
            if (more) {
                const int k0 = (chunk + 1) * KC;
                rx0 = *(const float4*)(x + (size_t)sxb * 6 * NN + k0 + sxk);
                rx1 = *(const float4*)(x + (size_t)(sxb + 16) * 6 * NN + k0 + sxk);
                rw0 = *(const float4*)(w1 + (size_t)(k0 + swr) * 32 + swc);
                rw1 = *(const float4*)(w1 + (size_t)(k0 + swr + 32) * 32 + swc);
            }
            const float* xc = xs[cur];
            const float* wc = ws1[cur];
            #pragma unroll
            for (int i = 0; i < 8; ++i) {
                const int k = ks + 8 * i;
                const float4 wa = *(const float4*)(wc + k * WP + cg * 8);
                const float4 wb = *(const float4*)(wc + k * WP + cg * 8 + 4);
                float xv[4];
                #pragma unroll
                for (int j = 0; j < 4; ++j) xv[j] = xc[(bg + 8 * j) * XP + k];
                #pragma unroll
                for (int j = 0; j < 4; ++j) {
                    acc[j][0] = fmaf(xv[j], wa.x, acc[j][0]);
                    acc[j][1] = fmaf(xv[j], wa.y, acc[j][1]);
                    acc[j][2] = fmaf(xv[j], wa.z, acc[j][2]);
                    acc[j][3] = fmaf(xv[j], wa.w, acc[j][3]);
                    acc[j][4] = fmaf(xv[j], wb.x, acc[j][4]);
                    acc[j][5] = fmaf(xv[j], wb.y, acc[j][5]);
                    acc[j][6] = fmaf(xv[j], wb.z, acc[j][6]);
                    acc[j][7] = fmaf(xv[j], wb.w, acc[j][7]);
                }
            }
            if (more) {
                const int nb = cur ^ 1;
                *(float4*)(xs[nb] + sxb * XP + sxk) = rx0;
                *(float4*)(xs[nb] + (sxb + 16) * XP + sxk) = rx1;
                *(float4*)(ws1[nb] + swr * WP + swc) = rw0;
                *(float4*)(ws1[nb] + (swr + 32) * WP + swc) = rw1;
            }
            __syncthreads();
            cur ^= 1;
        }

        #pragma unroll
        for (int off = 1; off < 8; off <<= 1) {
            #pragma unroll
            for (int j = 0; j < 4; ++j)
                #pragma unroll
                for (int c = 0; c < 8; ++c)
                    acc[j][c] += __shfl_xor(acc[j][c], off, 64);
        }
        if (ks == 0) {
            float* hp = h_part + (size_t)blockIdx.x * 1024;
            #pragma unroll
            for (int j = 0; j < 4; ++j) {
                const int b = bg + 8 * j;
                #pragma unroll
                for (int c = 0; c < 8; ++c)
                    hp[b * 32 + cg * 8 + c] = acc[j][c];
            }
        }
    } else if (blockIdx.x < G1 + CPB) {
        // ---- hi-channel copy: 32 b x 307200 floats = 2457600 float4
        const int cb = blockIdx.x - G1;
        for (long i = (long)cb * 256 + tid; i < 2457600L; i += (long)CPB * 256) {
            const int b = (int)(i / 76800);           // 76800 = 307200/4
            const int rem = (int)(i - (long)b * 76800);
            const size_t off = (size_t)b * (6 * NN) + K3N + (size_t)rem * 4;
            *(float4*)(out + off) = *(const float4*)(x + off);
        }
    } else {
        // ---- pts1[t][j] = mean_s A[j][tess[t,s]]
        const int t = blockIdx.x - G1 - CPB;
        const int* tr = tess + t * SS;
        float s0 = 0.f, s1 = 0.f, s2 = 0.f;
        for (int s = tid; s < SS; s += 256) {
            const int idx = tr[s];
            s0 += A[idx]; s1 += A[NN + idx]; s2 += A[2 * NN + idx];
        }
        #pragma unroll
        for (int o = 32; o > 0; o >>= 1) {
            s0 += __shfl_down(s0, o, 64);
            s1 += __shfl_down(s1, o, 64);
            s2 += __shfl_down(s2, o, 64);
        }
        __shared__ float red[4 * 3];
        const int lane = tid & 63, wv = tid >> 6;
        if (lane == 0) { red[wv * 3] = s0; red[wv * 3 + 1] = s1; red[wv * 3 + 2] = s2; }
        __syncthreads();
        if (tid < 3) {
            const float s = red[tid] + red[3 + tid] + red[6 + tid] + red[9 + tid];
            pts1[t * 3 + tid] = s * (1.0f / SS);
        }
    }
}

// ---------------- KB: h-reduce + rigid params, 32 blocks (one per b)
__global__ __launch_bounds__(256) void kb_rigid(const float* __restrict__ h_part,
                                                const float* __restrict__ b1,
                                                const float* __restrict__ w2,
                                                const float* __restrict__ b2,
                                                const float* __restrict__ sz,
                                                float* __restrict__ RT) {
    const int bb = blockIdx.x;
    __shared__ float part[8][32];
    __shared__ float hsh[32];
    const int c = threadIdx.x & 31, g = threadIdx.x >> 5;
    float s = 0.f;
    for (int j = g; j < G1; j += 8) s += h_part[(size_t)j * 1024 + bb * 32 + c];
    part[g][c] = s;
    __syncthreads();
    if (threadIdx.x < 32) {
        float acc = 0.f;
        #pragma unroll
        for (int g2 = 0; g2 < 8; ++g2) acc += part[g2][threadIdx.x];
        hsh[threadIdx.x] = fmaxf(acc + b1[threadIdx.x], 0.f);
    }
    __syncthreads();
    const int t = threadIdx.x;
    if (t < TT) {
        float z[3];
        #pragma unroll
        for (int j = 0; j < 3; ++j) {
            const int col = 6 * t + 3 + j;
            float s2 = b2[col];
            #pragma unroll 8
            for (int cc = 0; cc < 32; ++cc) s2 = fmaf(hsh[cc], w2[cc * 384 + col], s2);
            z[j] = tanhf(s2);
        }
        float c0, s0, c1, s1, c2, s2v;
        sincosf(PI_F * z[0], &s0, &c0);
        sincosf(PI_F * z[1], &s1, &c1);
        sincosf(PI_F * z[2], &s2v, &c2);
        const float R00 = c0 * c1;
        const float R01 = -s0 * c2 + c0 * s1 * s2v;
        const float R02 = s0 * s2v + c0 * s1 * c2;
        const float R10 = s0 * c1;
        const float R11 = c0 * c2 + s0 * s1 * s2v;
        const float R12 = -c0 * s2v + s0 * s1 * c2;
        const float R20 = -s1;
        const float R21 = c1 * s2v;
        const float R22 = c1 * c2;
        const float szx = sz[0], szy = sz[1], szz = sz[2];
        const float cx = 0.5f * szx, cy = 0.5f * szy, cz = 0.5f * szz;
        const float T0 = z[0] * szx + cx - (cx * R00 + cy * R10 + cz * R20);
        const float T1 = z[1] * szy + cy - (cx * R01 + cy * R11 + cz * R21);
        const float T2 = z[2] * szz + cz - (cx * R02 + cy * R12 + cz * R22);
        float* o = RT + (bb * TT + t) * 12;
        o[0] = R00; o[1] = R10; o[2]  = R20; o[3]  = T0;
        o[4] = R01; o[5] = R11; o[6]  = R21; o[7]  = T1;
        o[8] = R02; o[9] = R12; o[10] = R22; o[11] = T2;
    }
}

// ---------------- K3: transform + scatter + pts2 (hi-copy moved to k1_mega)
__global__ __launch_bounds__(256) void k3_transform(const float* __restrict__ x,
                                                    const int* __restrict__ tess,
                                                    const float* __restrict__ RT,
                                                    float* __restrict__ out,
                                                    float* __restrict__ pts2) {
    const int blk = blockIdx.x;
    const int b = blk / TT, t = blk % TT;
    const float* p = RT + blk * 12;
    const float M00 = p[0], M01 = p[1], M02 = p[2], T0 = p[3];
    const float M10 = p[4], M11 = p[5], M12 = p[6], T1 = p[7];
    const float M20 = p[8], M21 = p[9], M22 = p[10], T2 = p[11];
    const float* xb = x + (size_t)b * 6 * NN;
    float* ob = out + (size_t)b * 6 * NN;
    const int* tr = tess + t * SS;
    float s0 = 0.f, s1 = 0.f, s2 = 0.f;
    for (int s = threadIdx.x; s < SS; s += 256) {
        const int idx = tr[s];
        const float x0 = xb[idx], x1 = xb[NN + idx], x2 = xb[2 * NN + idx];
        const float y0 = fmaf(M00, x0, fmaf(M01, x1, fmaf(M02, x2, T0)));
        const float y1 = fmaf(M10, x0, fmaf(M11, x1, fmaf(M12, x2, T1)));
        const float y2 = fmaf(M20, x0, fmaf(M21, x1, fmaf(M22, x2, T2)));
        ob[idx] = y0; ob[NN + idx] = y1; ob[2 * NN + idx] = y2;
        s0 += y0; s1 += y1; s2 += y2;
    }
    #pragma unroll
    for (int o = 32; o > 0; o >>= 1) {
        s0 += __shfl_down(s0, o, 64);
        s1 += __shfl_down(s1, o, 64);
        s2 += __shfl_down(s2, o, 64);
    }
    __shared__ float red[4 * 3];
    const int lane = threadIdx.x & 63, wv = threadIdx.x >> 6;
    if (lane == 0) { red[wv * 3] = s0; red[wv * 3 + 1] = s1; red[wv * 3 + 2] = s2; }
    __syncthreads();
    if (threadIdx.x < 3) {
        const float s = red[threadIdx.x] + red[3 + threadIdx.x] + red[6 + threadIdx.x] + red[9 + threadIdx.x];
        pts2[blk * 3 + threadIdx.x] = s * (1.0f / SS);
    }
}

// ---------------- K5: reg[b] = sum_{t,u} (mask[t,u]*(d1[t,u]-d2[b,t,u]))^2
__global__ __launch_bounds__(256) void k5_reg(const float* __restrict__ pts1,
                                              const float* __restrict__ pts2,
                                              const float* __restrict__ mask,
                                              float* __restrict__ out) {
    const int b = blockIdx.x;
    __shared__ float p1[TT * 3], p2[TT * 3];
    for (int i = threadIdx.x; i < TT * 3; i += 256) {
        p1[i] = pts1[i];
        p2[i] = pts2[b * TT * 3 + i];
    }
    __syncthreads();
    float acc = 0.f;
    for (int pr = threadIdx.x; pr < TT * TT; pr += 256) {
        const int t = pr >> 6, u = pr & 63;
        float dx = p1[t * 3] - p1[u * 3];
        float dy = p1[t * 3 + 1] - p1[u * 3 + 1];
        float dz = p1[t * 3 + 2] - p1[u * 3 + 2];
        const float d1 = sqrtf(dx * dx + dy * dy + dz * dz + 1e-12f);
        dx = p2[t * 3] - p2[u * 3];
        dy = p2[t * 3 + 1] - p2[u * 3 + 1];
        dz = p2[t * 3 + 2] - p2[u * 3 + 2];
        const float d2 = sqrtf(dx * dx + dy * dy + dz * dz + 1e-12f);
        const float d = mask[pr] * (d1 - d2);
        acc = fmaf(d, d, acc);
    }
    #pragma unroll
    for (int o = 32; o > 0; o >>= 1) acc += __shfl_down(acc, o, 64);
    __shared__ float red[4];
    const int lane = threadIdx.x & 63, wv = threadIdx.x >> 6;
    if (lane == 0) red[wv] = acc;
    __syncthreads();
    if (threadIdx.x == 0) {
        out[(size_t)BB * 6 * NN + b] = red[0] + red[1] + red[2] + red[3];
    }
}

extern "C" void kernel_launch(void* const* d_in, const int* in_sizes, int n_in,
                              void* d_out, int out_size, void* d_ws, size_t ws_size,
                              hipStream_t stream) {
    const float* x    = (const float*)d_in[0];
    const float* w1   = (const float*)d_in[1];
    const float* b1   = (const float*)d_in[2];
    const float* w2   = (const float*)d_in[3];
    const float* b2   = (const float*)d_in[4];
    const float* A    = (const float*)d_in[5];
    const float* mask = (const float*)d_in[6];
    const float* sz   = (const float*)d_in[7];
    const int*   tess = (const int*)d_in[8];
    float* out = (float*)d_out;
    float* ws  = (float*)d_ws;

    float* h_part = ws;                           // G1*1024 (2 MB)
    float* RT     = h_part + (size_t)G1 * 1024;   // 2048*12
    float* pts2   = RT + BB * TT * 12;            // 2048*3
    float* pts1   = pts2 + BB * TT * 3;           // 64*3

    k1_mega<<<G1 + CPB + TT, 256, 0, stream>>>(x, w1, A, tess, h_part, out, pts1);
    kb_rigid<<<BB, 256, 0, stream>>>(h_part, b1, w2, b2, sz, RT);
    k3_transform<<<BB * TT, 256, 0, stream>>>(x, tess, RT, out, pts2);
    k5_reg<<<BB, 256, 0, stream>>>(pts1, pts2, mask, out);
}